// Round 4
// baseline (68.992 us; speedup 1.0000x reference)
//
#include <hip/hip_runtime.h>
#include <cstddef>

// YOLO decode: out[b, ((h*W+w)*3+a), attr] = f(x[b, a*85+attr, h, w])
//   attr 0: (sigmoid(v) + w) * stride
//   attr 1: (sigmoid(v) + h) * stride
//   attr 2: exp(v) * anchor_w_px
//   attr 3: exp(v) * anchor_h_px
//   attr 4: sigmoid(v)
//   attr>=5: sigmoid(idf[attr-5] * v)
//
// One wave = 4 pixels of one (batch, scale). Lane l loads channels l+64k
// (k=0..3) as one float4 each (4 consecutive pixels of that channel) -> 4
// independent 64B loads issued before any use (MLP=4). Transform has a
// per-(lane,k)-uniform attr branch. LDS writes at stride 255: consecutive
// lanes -> consecutive banks (conflict-free). LDS image is pre-shifted by s
// so copy-out float4 reads are 16B-aligned ds_read_b128 and global stores
// are aligned dwordx4 (head = b&3 scalars).

#define NATTR 85
#define NCH 255

static constexpr int TOTROWS = (76 * 76 + 38 * 38 + 19 * 19) * 3;  // 22743

static __device__ __forceinline__ float sigmoidf_(float x) {
  return 1.0f / (1.0f + __expf(-x));
}

template <int SCALE>
struct Cfg {
  static constexpr int W = (SCALE == 0) ? 76 : (SCALE == 1) ? 38 : 19;
  static constexpr int HW = W * W;
  static constexpr int WPB = (HW + 3) / 4;  // waves per batch image: 1444/361/91
  static constexpr float STRIDE = 608.0f / (float)W;
  static constexpr int ROWBASE =
      (SCALE == 0) ? 0 : (SCALE == 1) ? 76 * 76 * 3 : (76 * 76 * 3 + 38 * 38 * 3);
  static constexpr float AW0 = (SCALE == 0) ? 10.f : (SCALE == 1) ? 30.f : 116.f;
  static constexpr float AW1 = (SCALE == 0) ? 16.f : (SCALE == 1) ? 62.f : 156.f;
  static constexpr float AW2 = (SCALE == 0) ? 33.f : (SCALE == 1) ? 59.f : 373.f;
  static constexpr float AH0 = (SCALE == 0) ? 13.f : (SCALE == 1) ? 61.f : 90.f;
  static constexpr float AH1 = (SCALE == 0) ? 30.f : (SCALE == 1) ? 45.f : 198.f;
  static constexpr float AH2 = (SCALE == 0) ? 23.f : (SCALE == 1) ? 119.f : 326.f;
};

template <int SCALE>
static __device__ __forceinline__ float xf(int a, int attr, int p, float v,
                                           const float* __restrict__ sidf) {
  using C = Cfg<SCALE>;
  if (attr >= 5) return sigmoidf_(sidf[attr - 5] * v);  // 80/85 channels
  if (attr == 4) return sigmoidf_(v);
  if (attr == 2) {
    const float aw = (a == 0) ? C::AW0 : (a == 1) ? C::AW1 : C::AW2;
    return __expf(v) * aw;
  }
  if (attr == 3) {
    const float ah = (a == 0) ? C::AH0 : (a == 1) ? C::AH1 : C::AH2;
    return __expf(v) * ah;
  }
  const int h = p / C::W;  // constexpr W -> magic mul
  const int w = p - h * C::W;
  return (sigmoidf_(v) + (float)((attr == 0) ? w : h)) * C::STRIDE;
}

// Phase A: global -> transform -> LDS (per-wave, no barrier inside).
template <int SCALE>
static __device__ __forceinline__ void stageA(int wgid, int lane,
                                              const float* __restrict__ x,
                                              const float* __restrict__ sidf,
                                              float* __restrict__ lw,
                                              size_t& off_out, int& np_out) {
  using C = Cfg<SCALE>;
  const int b = wgid / C::WPB;
  const int t = wgid - b * C::WPB;
  const int p0 = t * 4;
  const int rem = C::HW - p0;
  const int np = rem < 4 ? rem : 4;
  const size_t off = ((size_t)b * TOTROWS + C::ROWBASE + (size_t)p0 * 3) * NATTR;
  const int head = (int)((4 - (off & 3)) & 3);
  const int s = (4 - head) & 3;  // LDS shift so s+head is 16B-aligned
  const float* src = x + (size_t)b * ((size_t)NCH * C::HW) + p0;

  if constexpr (C::HW % 4 == 0) {
    // p0 % 4 == 0 and HW % 4 == 0 -> aligned float4, and np is always 4
    float4 r[4];
#pragma unroll
    for (int k = 0; k < 4; ++k) {
      const int c = lane + 64 * k;
      if (c < NCH) r[k] = *reinterpret_cast<const float4*>(src + (size_t)c * C::HW);
    }
#pragma unroll
    for (int k = 0; k < 4; ++k) {
      const int c = lane + 64 * k;
      if (c < NCH) {
        const int a = c / NATTR;
        const int attr = c - a * NATTR;
        float* dl = lw + s + c;
        dl[0]       = xf<SCALE>(a, attr, p0 + 0, r[k].x, sidf);
        dl[NCH]     = xf<SCALE>(a, attr, p0 + 1, r[k].y, sidf);
        dl[2 * NCH] = xf<SCALE>(a, attr, p0 + 2, r[k].z, sidf);
        dl[3 * NCH] = xf<SCALE>(a, attr, p0 + 3, r[k].w, sidf);
      }
    }
  } else {
    // odd HW (scale 2): scalar loads, still all prefetched before use
    float rs[4][4];
#pragma unroll
    for (int k = 0; k < 4; ++k) {
      const int c = lane + 64 * k;
      if (c < NCH) {
        const float* sp = src + (size_t)c * C::HW;
#pragma unroll
        for (int m = 0; m < 4; ++m)
          if (m < np) rs[k][m] = sp[m];
      }
    }
#pragma unroll
    for (int k = 0; k < 4; ++k) {
      const int c = lane + 64 * k;
      if (c < NCH) {
        const int a = c / NATTR;
        const int attr = c - a * NATTR;
        float* dl = lw + s + c;
#pragma unroll
        for (int m = 0; m < 4; ++m)
          if (m < np) dl[m * NCH] = xf<SCALE>(a, attr, p0 + m, rs[k][m], sidf);
      }
    }
  }
  off_out = off;
  np_out = np;
}

// Phase B: LDS -> global, scale-independent. lw[s + j] holds dst[off + j].
static __device__ __forceinline__ void writeB(int lane, const float* __restrict__ lw,
                                              float* __restrict__ out, size_t off,
                                              int np) {
  const int total = np * NCH;
  const int head = (int)((4 - (off & 3)) & 3);
  const int s = (4 - head) & 3;
  float* dst = out + off;
  if (np == 4) {
    if (lane < head) dst[lane] = lw[s + lane];
    const int nvec = (total - head) >> 2;  // 255 or 254
    const float4* lv = reinterpret_cast<const float4*>(lw + s + head);  // 16B-aligned
#pragma unroll
    for (int k = 0; k < 4; ++k) {
      const int v = lane + 64 * k;
      if (v < nvec) *reinterpret_cast<float4*>(dst + head + 4 * v) = lv[v];
    }
    const int done = head + 4 * nvec;
    if (lane < total - done) dst[done + lane] = lw[s + done + lane];
  } else {
    for (int j = lane; j < total; j += 64) dst[j] = lw[s + j];
  }
}

__global__ __launch_bounds__(256, 8) void yolo_all(
    const float* __restrict__ x0, const float* __restrict__ x1,
    const float* __restrict__ x2, const float* __restrict__ idf,
    float* __restrict__ out, int bs) {
  __shared__ __align__(16) float lds[4][1024];
  __shared__ float sidf[80];
  if (threadIdx.x < 80) sidf[threadIdx.x] = idf[threadIdx.x];
  __syncthreads();

  const int wid = threadIdx.x >> 6;
  const int lane = threadIdx.x & 63;
  float* lw = lds[wid];
  const int g = blockIdx.x * 4 + wid;
  const int n0 = Cfg<0>::WPB * bs;
  const int n1 = Cfg<1>::WPB * bs;

  size_t off;
  int np;
  if (g < n0) {
    stageA<0>(g, lane, x0, sidf, lw, off, np);
  } else if (g < n0 + n1) {
    stageA<1>(g - n0, lane, x1, sidf, lw, off, np);
  } else {
    stageA<2>(g - n0 - n1, lane, x2, sidf, lw, off, np);
  }
  __syncthreads();  // uniform: makes cross-lane LDS exchange well-defined
  writeB(lane, lw, out, off, np);
}

extern "C" void kernel_launch(void* const* d_in, const int* in_sizes, int n_in,
                              void* d_out, int out_size, void* d_ws, size_t ws_size,
                              hipStream_t stream) {
  const float* x0 = (const float*)d_in[0];
  const float* x1 = (const float*)d_in[1];
  const float* x2 = (const float*)d_in[2];
  const float* idf = (const float*)d_in[3];
  float* out = (float*)d_out;

  const int bs = in_sizes[0] / (NCH * 76 * 76);  // 16
  const int nwaves = (Cfg<0>::WPB + Cfg<1>::WPB + Cfg<2>::WPB) * bs;  // 1896*bs, %4==0
  const int nb = nwaves / 4;

  yolo_all<<<dim3(nb), dim3(256), 0, stream>>>(x0, x1, x2, idf, out, bs);
}

// Round 5
// 54.605 us; speedup vs baseline: 1.2635x; 1.2635x over previous
//
#include <hip/hip_runtime.h>
#include <cstddef>

// YOLO decode: out[b, ((h*W+w)*3+a), attr] = f(x[b, a*85+attr, h, w])
//   attr 0: (sigmoid(v) + w) * stride
//   attr 1: (sigmoid(v) + h) * stride
//   attr 2: exp(v) * anchor_w_px
//   attr 3: exp(v) * anchor_h_px
//   attr 4: sigmoid(v)
//   attr>=5: sigmoid(idf[attr-5] * v)
//
// Block = 512 threads, tile = 32 pixels of one (batch, scale).
// Staging: 8 consecutive lanes own one channel (8 x float4 = 128B contiguous
// per channel per wave-load -> full-line HBM transactions). Transform applied
// at staging (attr known per quad). LDS written [p][c] stride 255 (2-way bank
// alias only). Copy-out: LDS image pre-shifted so float4 reads are 16B-aligned
// ds_read_b128 and global stores are aligned dwordx4.

#define NATTR 85
#define NCH 255
#define TILE 32        // pixels per block
#define QPT 8          // float4 quads per channel tile (TILE/4)

static constexpr int TOTROWS = (76 * 76 + 38 * 38 + 19 * 19) * 3;  // 22743

static __device__ __forceinline__ float sigmoidf_(float x) {
  return 1.0f / (1.0f + __expf(-x));
}

template <int SCALE>
struct Cfg {
  static constexpr int W = (SCALE == 0) ? 76 : (SCALE == 1) ? 38 : 19;
  static constexpr int HW = W * W;
  static constexpr int TILES = (HW + TILE - 1) / TILE;  // 181 / 46 / 12
  static constexpr float STRIDE = 608.0f / (float)W;
  static constexpr int ROWBASE =
      (SCALE == 0) ? 0 : (SCALE == 1) ? 76 * 76 * 3 : (76 * 76 * 3 + 38 * 38 * 3);
  static constexpr float AW0 = (SCALE == 0) ? 10.f : (SCALE == 1) ? 30.f : 116.f;
  static constexpr float AW1 = (SCALE == 0) ? 16.f : (SCALE == 1) ? 62.f : 156.f;
  static constexpr float AW2 = (SCALE == 0) ? 33.f : (SCALE == 1) ? 59.f : 373.f;
  static constexpr float AH0 = (SCALE == 0) ? 13.f : (SCALE == 1) ? 61.f : 90.f;
  static constexpr float AH1 = (SCALE == 0) ? 30.f : (SCALE == 1) ? 45.f : 198.f;
  static constexpr float AH2 = (SCALE == 0) ? 23.f : (SCALE == 1) ? 119.f : 326.f;
};

template <int SCALE>
static __device__ __forceinline__ float xf(int a, int attr, int p, float v,
                                           const float* __restrict__ sidf) {
  using C = Cfg<SCALE>;
  if (attr >= 5) return sigmoidf_(sidf[attr - 5] * v);  // 80/85 channels
  if (attr == 4) return sigmoidf_(v);
  if (attr == 2) {
    const float aw = (a == 0) ? C::AW0 : (a == 1) ? C::AW1 : C::AW2;
    return __expf(v) * aw;
  }
  if (attr == 3) {
    const float ah = (a == 0) ? C::AH0 : (a == 1) ? C::AH1 : C::AH2;
    return __expf(v) * ah;
  }
  const int h = p / C::W;  // constexpr W -> magic mul
  const int w = p - h * C::W;
  return (sigmoidf_(v) + (float)((attr == 0) ? w : h)) * C::STRIDE;
}

template <int SCALE>
static __device__ __forceinline__ void decode_tile(
    int b, int t, const float* __restrict__ x, float* __restrict__ out,
    const float* __restrict__ sidf, float* __restrict__ lds) {
  using C = Cfg<SCALE>;
  const int p0 = t * TILE;
  const int rem = C::HW - p0;
  const int np = rem < TILE ? rem : TILE;
  const size_t off = ((size_t)b * TOTROWS + C::ROWBASE + (size_t)p0 * 3) * NATTR;
  const int head = (int)((4 - (off & 3)) & 3);
  const int s = (4 - head) & 3;  // LDS shift so lds[s+head] is 16B-aligned
  const float* src = x + (size_t)b * ((size_t)C::HW * NCH) + p0;

  if ((C::HW % 4 == 0) && np == TILE) {
    // full tile: thread owns (channel c, quad v); 8 consecutive lanes share a
    // channel -> 128B contiguous per channel per wave-load
    for (int i = threadIdx.x; i < NCH * QPT; i += 512) {
      const int c = i >> 3;
      const int v = i & 7;
      const float4 val = *reinterpret_cast<const float4*>(src + (size_t)c * C::HW + 4 * v);
      const int a = c / NATTR;
      const int attr = c - a * NATTR;
      const int pb = p0 + 4 * v;
      float* dl = lds + s + (4 * v) * NCH + c;  // [p][c], stride 255
      dl[0]       = xf<SCALE>(a, attr, pb + 0, val.x, sidf);
      dl[NCH]     = xf<SCALE>(a, attr, pb + 1, val.y, sidf);
      dl[2 * NCH] = xf<SCALE>(a, attr, pb + 2, val.z, sidf);
      dl[3 * NCH] = xf<SCALE>(a, attr, pb + 3, val.w, sidf);
    }
  } else {
    // tail / odd-HW tile: scalar guarded (consecutive lanes -> consecutive p)
    for (int i = threadIdx.x; i < NCH * TILE; i += 512) {
      const int c = i >> 5;
      const int p = i & 31;
      if (p < np) {
        const int a = c / NATTR;
        const int attr = c - a * NATTR;
        const float v = src[(size_t)c * C::HW + p];
        lds[s + p * NCH + c] = xf<SCALE>(a, attr, p0 + p, v, sidf);
      }
    }
  }
  __syncthreads();

  float* dst = out + off;
  const int total = np * NCH;

  if (np == TILE) {
    if (threadIdx.x < head) dst[threadIdx.x] = lds[s + threadIdx.x];
    const int nvec = (total - head) >> 2;  // 2040 or 2039
    const float4* lv = reinterpret_cast<const float4*>(lds + s + head);  // aligned
    for (int k = threadIdx.x; k < nvec; k += 512)
      *reinterpret_cast<float4*>(dst + head + 4 * k) = lv[k];
    const int done = head + 4 * nvec;
    if (threadIdx.x < total - done) dst[done + threadIdx.x] = lds[s + done + threadIdx.x];
  } else {
    for (int j = threadIdx.x; j < total; j += 512) dst[j] = lds[s + j];
  }
}

__global__ __launch_bounds__(512, 8) void yolo_all(
    const float* __restrict__ x0, const float* __restrict__ x1,
    const float* __restrict__ x2, const float* __restrict__ idf,
    float* __restrict__ out, int bs) {
  __shared__ __align__(16) float lds[TILE * NCH + 4];
  __shared__ float sidf[80];
  if (threadIdx.x < 80) sidf[threadIdx.x] = idf[threadIdx.x];
  __syncthreads();

  const int nb0 = Cfg<0>::TILES * bs;
  const int nb1 = Cfg<1>::TILES * bs;
  int blk = blockIdx.x;
  if (blk < nb0) {
    decode_tile<0>(blk / Cfg<0>::TILES, blk % Cfg<0>::TILES, x0, out, sidf, lds);
  } else if (blk < nb0 + nb1) {
    blk -= nb0;
    decode_tile<1>(blk / Cfg<1>::TILES, blk % Cfg<1>::TILES, x1, out, sidf, lds);
  } else {
    blk -= nb0 + nb1;
    decode_tile<2>(blk / Cfg<2>::TILES, blk % Cfg<2>::TILES, x2, out, sidf, lds);
  }
}

extern "C" void kernel_launch(void* const* d_in, const int* in_sizes, int n_in,
                              void* d_out, int out_size, void* d_ws, size_t ws_size,
                              hipStream_t stream) {
  const float* x0 = (const float*)d_in[0];
  const float* x1 = (const float*)d_in[1];
  const float* x2 = (const float*)d_in[2];
  const float* idf = (const float*)d_in[3];
  float* out = (float*)d_out;

  const int bs = in_sizes[0] / (NCH * 76 * 76);  // 16
  const int nb = (Cfg<0>::TILES + Cfg<1>::TILES + Cfg<2>::TILES) * bs;  // 239*bs

  yolo_all<<<dim3(nb), dim3(512), 0, stream>>>(x0, x1, x2, idf, out, bs);
}